// Round 2
// baseline (724.877 us; speedup 1.0000x reference)
//
#include <hip/hip_runtime.h>
#include <hip/hip_bf16.h>
#include <stdint.h>

typedef __bf16 bf16;
typedef __bf16 bf16x4 __attribute__((ext_vector_type(4)));
typedef __bf16 bf16x8 __attribute__((ext_vector_type(8)));
typedef float f32x4 __attribute__((ext_vector_type(4)));

#define MFMA_BF16(a, b, c) __builtin_amdgcn_mfma_f32_16x16x32_bf16((a), (b), (c), 0, 0, 0)

// ---------------------------------------------------------------------------
// helpers
// ---------------------------------------------------------------------------
__device__ __forceinline__ void load16f(const float* p, float* r) {
#pragma unroll
  for (int i = 0; i < 4; ++i) {
    float4 v = *(const float4*)(p + 4 * i);
    r[4 * i + 0] = v.x; r[4 * i + 1] = v.y; r[4 * i + 2] = v.z; r[4 * i + 3] = v.w;
  }
}

__device__ __forceinline__ void store16_bf16(bf16* dst, const float* r) {
  bf16x8 v0, v1;
#pragma unroll
  for (int i = 0; i < 8; ++i) { v0[i] = (bf16)r[i]; v1[i] = (bf16)r[8 + i]; }
  *(bf16x8*)(dst) = v0;
  *(bf16x8*)(dst + 8) = v1;
}

// ---------------------------------------------------------------------------
// Kernel 0: precompute per-fragment rel-pos bias, pre-multiplied by log2(e)
// (softmax runs in exp2 domain -> single v_exp_f32 per element).
// Layout biasF[h][qt][kt][g][li][r], sigma key order baked in:
//   key = 32*(kt>>1) + 8*g + 4*(kt&1) + r
// 32768 float4 entries = 512 KB (lives in d_out, overwritten by proj later).
// ---------------------------------------------------------------------------
__global__ void bias_pre(const float* __restrict__ rel, float* __restrict__ biasF)
{
  const int t = blockIdx.x * 256 + threadIdx.x;          // 32768 threads
  const int li = t & 15, g = (t >> 4) & 3, kt = (t >> 6) & 15;
  const int qt = (t >> 10) & 3, h = (t >> 12) & 7;
  const int n = qt * 16 + li, ni = n >> 3, nj = n & 7;
  float4 v;
  float* vp = (float*)&v;
#pragma unroll
  for (int r = 0; r < 4; ++r) {
    const int key = 32 * (kt >> 1) + 8 * g + 4 * (kt & 1) + r;
    const int ki = key >> 4, kj = key & 15;
    const int bi = (ni + 19 - ki) * 31 + (nj + 19 - kj);
    vp[r] = rel[bi * 8 + h] * 1.4426950408889634f;
  }
  ((float4*)biasF)[t] = v;
}

// ---------------------------------------------------------------------------
// Kernel 1: qkv = x @ qkv_w.T + qkv_b  (A fp32 -> bf16 in staging)
// M=131072, N=768, K=256.
// Q,K written [head][token][32]; V written TRANSPOSED [h*32+d][token].
// ---------------------------------------------------------------------------
__global__ __launch_bounds__(256, 2)
void qkv_gemm(const float* __restrict__ X, const float* __restrict__ W,
              const float* __restrict__ bias,
              bf16* __restrict__ Qb, bf16* __restrict__ Kb, bf16* __restrict__ Vb)
{
  constexpr int K = 256;
  constexpr int LD = 40;
  __shared__ bf16 As[128 * LD];
  __shared__ bf16 Bs[128 * LD];

  const int tid = threadIdx.x;
  const int lane = tid & 63, wave = tid >> 6;
  const int bn = blockIdx.x % 6, bm = blockIdx.x / 6;
  const int m0 = bm * 128, n0 = bn * 128;
  const int sr = tid >> 1, sc = (tid & 1) * 16;
  const int wr = (wave >> 1) * 64, wc = (wave & 1) * 64;
  const int g = lane >> 4, li = lane & 15;

  const f32x4 fzero = {0.f, 0.f, 0.f, 0.f};
  f32x4 acc[4][4];
#pragma unroll
  for (int i = 0; i < 4; ++i)
#pragma unroll
    for (int j = 0; j < 4; ++j) acc[i][j] = fzero;

  const float* Ap = X + (size_t)(m0 + sr) * K + sc;
  const float* Bp = W + (size_t)(n0 + sr) * K + sc;
  float aR[16], bR[16];
  load16f(Ap, aR); load16f(Bp, bR);

#pragma unroll 1
  for (int kt = 0; kt < 8; ++kt) {
    store16_bf16(&As[sr * LD + sc], aR);
    store16_bf16(&Bs[sr * LD + sc], bR);
    __syncthreads();
    if (kt < 7) { Ap += 32; Bp += 32; load16f(Ap, aR); load16f(Bp, bR); }
    bf16x8 af[4], bfr[4];
#pragma unroll
    for (int t = 0; t < 4; ++t) {
      af[t]  = *(const bf16x8*)&As[(wr + t * 16 + li) * LD + g * 8];
      bfr[t] = *(const bf16x8*)&Bs[(wc + t * 16 + li) * LD + g * 8];
    }
#pragma unroll
    for (int i = 0; i < 4; ++i)
#pragma unroll
      for (int j = 0; j < 4; ++j)
        acc[i][j] = MFMA_BF16(af[i], bfr[j], acc[i][j]);
    __syncthreads();
  }

  // epilogue: C row = m0+wr+i*16+g*4+r (mult of 4), col = n0+wc+j*16+li
#pragma unroll
  for (int i = 0; i < 4; ++i) {
    const int row = m0 + wr + i * 16 + g * 4;
#pragma unroll
    for (int j = 0; j < 4; ++j) {
      const int col = n0 + wc + j * 16 + li;
      const float bv = bias[col];
      const int which = col >> 8;                 // 0=q 1=k 2=v
      if (which == 2) {
        // V transposed: Vb[(h*32+c)][token], 4 consecutive tokens -> 8B store
        const int hh = (col >> 5) & 7, c = col & 31;
        bf16x4 pv;
#pragma unroll
        for (int r = 0; r < 4; ++r) pv[r] = (bf16)(acc[i][j][r] + bv);
        *(bf16x4*)(Vb + (((size_t)(hh * 32 + c)) << 17) + row) = pv;
      } else {
        bf16* dst = which == 0 ? Qb : Kb;
        const size_t base = (size_t)((col >> 5) & 7) * (131072u * 32u) + (size_t)(col & 31);
#pragma unroll
        for (int r = 0; r < 4; ++r)
          dst[base + (size_t)(row + r) * 32u] = (bf16)(acc[i][j][r] + bv);
      }
    }
  }
}

// ---------------------------------------------------------------------------
// Kernel 2: window attention, LDS-free swapped-operand form.
// Block = (window, head), 4 waves; wave qt owns queries qt*16..qt*16+15.
//  QK^T:  S^T tile = mfma(A=K-tile, B=Q)  -> lane holds S[key][q=li]
//         sigma key order: key(kt,lane,r) = 32*(kt>>1)+8*g+4*(kt&1)+r
//         => PV B-fragment is in-lane, no exchange, no LDS.
//  softmax: in-register over 64 vals + shfl_xor(16,32); exp2 domain.
//  PV:    O^T = mfma(A=V^T, B=P^T), V^T read straight from global (bf16x4
//         halves, 4-token runs align with image boundary -> clean masking).
// ---------------------------------------------------------------------------
__global__ __launch_bounds__(256)
void win_attn(const bf16* __restrict__ Qb, const bf16* __restrict__ Kb,
              const bf16* __restrict__ Vt, const float* __restrict__ biasF,
              bf16* __restrict__ Ob)
{
  const int tid = threadIdx.x;
  const int lane = tid & 63, qt = tid >> 6;
  const int li = lane & 15, g = lane >> 4;
  const int bid = blockIdx.x;
  const int h = bid & 7, w = bid >> 3;
  const int b = w >> 8, wi = (w >> 4) & 15, wj = w & 15;
  const int btok = b << 14;

  // ---- Q fragment (B-operand): lane holds Q[q=qt*16+li][d = g*8 + 0..7]
  const int q = qt * 16 + li;
  const int tokq = btok + (wi * 8 + (q >> 3)) * 128 + (wj * 8 + (q & 7));
  const bf16x8 qf = *(const bf16x8*)(Qb + ((((size_t)h) << 17) + tokq) * 32 + g * 8);

  // ---- QK^T over 16 sigma-ordered key tiles ----
  const f32x4 z4 = {0.f, 0.f, 0.f, 0.f};
  f32x4 s[16];
  const int krow0 = wi * 8 + (li >> 3) - 4;
  const int kcol0 = wj * 8 + 8 * ((li >> 2) & 1) + (li & 3) - 4;
  const bf16* kb = Kb + ((((size_t)h) << 17) + btok) * 32 + g * 8;
#pragma unroll
  for (int kt = 0; kt < 16; ++kt) {
    const int gi = krow0 + 2 * (kt >> 1);
    const int gj = kcol0 + 4 * (kt & 1);
    bf16x8 kf = {};
    if (((unsigned)gi < 128u) && ((unsigned)gj < 128u))
      kf = *(const bf16x8*)(kb + (size_t)(gi * 128 + gj) * 32);
    s[kt] = MFMA_BF16(kf, qf, z4);
  }

  // ---- scale*log2e + bias (bias pre-multiplied by log2e) ----
  const float scaleL = 0.17677669529663687f * 1.4426950408889634f;
  const float* bF = biasF + (size_t)(((h * 4 + qt) * 16 * 4 + g) * 16 + li) * 4;
#pragma unroll
  for (int kt = 0; kt < 16; ++kt) {
    const float4 bv = *(const float4*)(bF + kt * 256);
    s[kt][0] = s[kt][0] * scaleL + bv.x;
    s[kt][1] = s[kt][1] * scaleL + bv.y;
    s[kt][2] = s[kt][2] * scaleL + bv.z;
    s[kt][3] = s[kt][3] * scaleL + bv.w;
  }

  // ---- softmax over 256 keys: per-lane 64 + shfl_xor across g-group ----
  float mx = -3.0e38f;
#pragma unroll
  for (int kt = 0; kt < 16; ++kt)
    mx = fmaxf(fmaxf(fmaxf(s[kt][0], s[kt][1]), fmaxf(s[kt][2], s[kt][3])), mx);
  mx = fmaxf(mx, __shfl_xor(mx, 16));
  mx = fmaxf(mx, __shfl_xor(mx, 32));

  float sum = 0.f;
  bf16x4 pk[16];
#pragma unroll
  for (int kt = 0; kt < 16; ++kt) {
    const float p0 = exp2f(s[kt][0] - mx);
    const float p1 = exp2f(s[kt][1] - mx);
    const float p2 = exp2f(s[kt][2] - mx);
    const float p3 = exp2f(s[kt][3] - mx);
    sum += (p0 + p1) + (p2 + p3);
    bf16x4 t; t[0] = (bf16)p0; t[1] = (bf16)p1; t[2] = (bf16)p2; t[3] = (bf16)p3;
    pk[kt] = t;
  }
  sum += __shfl_xor(sum, 16);
  sum += __shfl_xor(sum, 32);
  const float inv = __builtin_amdgcn_rcpf(sum);

  // ---- O^T = V^T * P^T ----
  f32x4 o0 = z4, o1 = z4;
  const int vgj = wj * 8 + 8 * (g & 1) - 4;               // 4-aligned col start
  const bool c0ok = (unsigned)vgj < 128u;
  const bool c1ok = (unsigned)(vgj + 4) < 128u;
  const bf16* v0p = Vt + (((size_t)(h * 32 + li)) << 17) + btok;
  const bf16* v1p = Vt + (((size_t)(h * 32 + 16 + li)) << 17) + btok;
#pragma unroll
  for (int ks = 0; ks < 8; ++ks) {
    const int gi = wi * 8 + 2 * ks + (g >> 1) - 4;
    const bool rok = (unsigned)gi < 128u;
    const int rowoff = gi * 128 + vgj;
    bf16x4 lo0 = {}, hi0 = {}, lo1 = {}, hi1 = {};
    if (rok && c0ok) { lo0 = *(const bf16x4*)(v0p + rowoff);
                       lo1 = *(const bf16x4*)(v1p + rowoff); }
    if (rok && c1ok) { hi0 = *(const bf16x4*)(v0p + rowoff + 4);
                       hi1 = *(const bf16x4*)(v1p + rowoff + 4); }
    const bf16x8 vf0 = __builtin_shufflevector(lo0, hi0, 0, 1, 2, 3, 4, 5, 6, 7);
    const bf16x8 vf1 = __builtin_shufflevector(lo1, hi1, 0, 1, 2, 3, 4, 5, 6, 7);
    const bf16x8 pb = __builtin_shufflevector(pk[2 * ks], pk[2 * ks + 1],
                                              0, 1, 2, 3, 4, 5, 6, 7);
    o0 = MFMA_BF16(vf0, pb, o0);
    o1 = MFMA_BF16(vf1, pb, o1);
  }

  // ---- epilogue: O[tokq][h*32 + dt*16 + 4g + r] = O^T/sum ----
  bf16* op = Ob + (size_t)tokq * 256 + h * 32 + 4 * g;
  bf16x4 w0, w1;
#pragma unroll
  for (int r = 0; r < 4; ++r) {
    w0[r] = (bf16)(o0[r] * inv);
    w1[r] = (bf16)(o1[r] * inv);
  }
  *(bf16x4*)(op) = w0;
  *(bf16x4*)(op + 16) = w1;
}

// ---------------------------------------------------------------------------
// Kernel 3: out = attn_out @ proj_w.T + proj_b   (fp32 output to d_out)
// ---------------------------------------------------------------------------
__global__ __launch_bounds__(256, 2)
void proj_gemm(const bf16* __restrict__ A, const float* __restrict__ W,
               const float* __restrict__ bias, float* __restrict__ Out)
{
  constexpr int K = 256;
  constexpr int LD = 40;
  __shared__ bf16 As[128 * LD];
  __shared__ bf16 Bs[128 * LD];

  const int tid = threadIdx.x;
  const int lane = tid & 63, wave = tid >> 6;
  const int bn = blockIdx.x & 1, bm = blockIdx.x >> 1;
  const int m0 = bm * 128, n0 = bn * 128;
  const int sr = tid >> 1, sc = (tid & 1) * 16;
  const int wr = (wave >> 1) * 64, wc = (wave & 1) * 64;
  const int g = lane >> 4, li = lane & 15;

  const f32x4 fzero = {0.f, 0.f, 0.f, 0.f};
  f32x4 acc[4][4];
#pragma unroll
  for (int i = 0; i < 4; ++i)
#pragma unroll
    for (int j = 0; j < 4; ++j) acc[i][j] = fzero;

  const bf16* Ap = A + (size_t)(m0 + sr) * K + sc;
  const float* Bp = W + (size_t)(n0 + sr) * K + sc;
  uint4 aV0, aV1; float bR[16];
  aV0 = *(const uint4*)(Ap); aV1 = *(const uint4*)(Ap + 8);
  load16f(Bp, bR);

#pragma unroll 1
  for (int kt = 0; kt < 8; ++kt) {
    *(uint4*)&As[sr * LD + sc] = aV0;
    *(uint4*)&As[sr * LD + sc + 8] = aV1;
    store16_bf16(&Bs[sr * LD + sc], bR);
    __syncthreads();
    if (kt < 7) {
      Ap += 32; Bp += 32;
      aV0 = *(const uint4*)(Ap); aV1 = *(const uint4*)(Ap + 8);
      load16f(Bp, bR);
    }
    bf16x8 af[4], bfr[4];
#pragma unroll
    for (int t = 0; t < 4; ++t) {
      af[t]  = *(const bf16x8*)&As[(wr + t * 16 + li) * LD + g * 8];
      bfr[t] = *(const bf16x8*)&Bs[(wc + t * 16 + li) * LD + g * 8];
    }
#pragma unroll
    for (int i = 0; i < 4; ++i)
#pragma unroll
      for (int j = 0; j < 4; ++j)
        acc[i][j] = MFMA_BF16(af[i], bfr[j], acc[i][j]);
    __syncthreads();
  }

#pragma unroll
  for (int i = 0; i < 4; ++i) {
    const int row = m0 + wr + i * 16 + g * 4;
#pragma unroll
    for (int j = 0; j < 4; ++j) {
      const int col = n0 + wc + j * 16 + li;
      const float bv = bias[col];
#pragma unroll
      for (int r = 0; r < 4; ++r)
        Out[(size_t)(row + r) * 256 + col] = acc[i][j][r] + bv;
    }
  }
}

// ---------------------------------------------------------------------------
extern "C" void kernel_launch(void* const* d_in, const int* in_sizes, int n_in,
                              void* d_out, int out_size, void* d_ws, size_t ws_size,
                              hipStream_t stream)
{
  const float* x       = (const float*)d_in[0];
  // d_in[1] = mask: unused by the reference
  const float* qkv_w   = (const float*)d_in[2];
  const float* qkv_b   = (const float*)d_in[3];
  const float* proj_w  = (const float*)d_in[4];
  const float* proj_b  = (const float*)d_in[5];
  const float* rel_tab = (const float*)d_in[6];
  float* out = (float*)d_out;

  char* ws = (char*)d_ws;
  bf16* Qb = (bf16*)(ws);                            // [8h][131072][32]   64 MiB
  bf16* Kb = (bf16*)(ws + (size_t)67108864);         // [8h][131072][32]   64 MiB
  bf16* Vt = (bf16*)(ws + (size_t)134217728);        // [8h*32d][131072]   64 MiB
  bf16* Ao = (bf16*)(ws + (size_t)201326592);        // [131072][256]      64 MiB
  // bias scratch (512 KB) lives in d_out; fully overwritten by proj_gemm.
  float* biasF = (float*)d_out;

  bias_pre<<<dim3(128), dim3(256), 0, stream>>>(rel_tab, biasF);
  qkv_gemm<<<dim3(6144), dim3(256), 0, stream>>>(x, qkv_w, qkv_b, Qb, Kb, Vt);
  win_attn<<<dim3(16384), dim3(256), 0, stream>>>(Qb, Kb, Vt, biasF, Ao);
  proj_gemm<<<dim3(2048), dim3(256), 0, stream>>>(Ao, proj_w, proj_b, out);
}

// Round 3
// 472.578 us; speedup vs baseline: 1.5339x; 1.5339x over previous
//
#include <hip/hip_runtime.h>
#include <hip/hip_bf16.h>
#include <stdint.h>

typedef __bf16 bf16;
typedef __bf16 bf16x4 __attribute__((ext_vector_type(4)));
typedef __bf16 bf16x8 __attribute__((ext_vector_type(8)));
typedef float f32x4 __attribute__((ext_vector_type(4)));

#define MFMA_BF16(a, b, c) __builtin_amdgcn_mfma_f32_16x16x32_bf16((a), (b), (c), 0, 0, 0)

// ---------------------------------------------------------------------------
// helpers
// ---------------------------------------------------------------------------
__device__ __forceinline__ void load16f(const float* p, float* r) {
#pragma unroll
  for (int i = 0; i < 4; ++i) {
    float4 v = *(const float4*)(p + 4 * i);
    r[4 * i + 0] = v.x; r[4 * i + 1] = v.y; r[4 * i + 2] = v.z; r[4 * i + 3] = v.w;
  }
}

__device__ __forceinline__ void store16_bf16(bf16* dst, const float* r) {
  bf16x8 v0, v1;
#pragma unroll
  for (int i = 0; i < 8; ++i) { v0[i] = (bf16)r[i]; v1[i] = (bf16)r[8 + i]; }
  *(bf16x8*)(dst) = v0;
  *(bf16x8*)(dst + 8) = v1;
}

// ---------------------------------------------------------------------------
// Kernel 0: precompute per-fragment rel-pos bias, pre-multiplied by log2(e).
// Layout biasF[h][qt][kt][g][li][r], sigma key order baked in:
//   key = 32*(kt>>1) + 8*g + 4*(kt&1) + r
// ---------------------------------------------------------------------------
__global__ void bias_pre(const float* __restrict__ rel, float* __restrict__ biasF)
{
  const int t = blockIdx.x * 256 + threadIdx.x;          // 32768 threads
  const int li = t & 15, g = (t >> 4) & 3, kt = (t >> 6) & 15;
  const int qt = (t >> 10) & 3, h = (t >> 12) & 7;
  const int n = qt * 16 + li, ni = n >> 3, nj = n & 7;
  float4 v;
  float* vp = (float*)&v;
#pragma unroll
  for (int r = 0; r < 4; ++r) {
    const int key = 32 * (kt >> 1) + 8 * g + 4 * (kt & 1) + r;
    const int ki = key >> 4, kj = key & 15;
    const int bi = (ni + 19 - ki) * 31 + (nj + 19 - kj);
    vp[r] = rel[bi * 8 + h] * 1.4426950408889634f;
  }
  ((float4*)biasF)[t] = v;
}

// ---------------------------------------------------------------------------
// Kernel 1: qkv = x @ qkv_w.T + qkv_b  (A fp32 -> bf16 in staging)
// Q,K written [head][token][32]; V written TRANSPOSED [h*32+d][token].
// ---------------------------------------------------------------------------
__global__ __launch_bounds__(256, 2)
void qkv_gemm(const float* __restrict__ X, const float* __restrict__ W,
              const float* __restrict__ bias,
              bf16* __restrict__ Qb, bf16* __restrict__ Kb, bf16* __restrict__ Vb)
{
  constexpr int K = 256;
  constexpr int LD = 40;
  __shared__ bf16 As[128 * LD];
  __shared__ bf16 Bs[128 * LD];

  const int tid = threadIdx.x;
  const int lane = tid & 63, wave = tid >> 6;
  const int bn = blockIdx.x % 6, bm = blockIdx.x / 6;
  const int m0 = bm * 128, n0 = bn * 128;
  const int sr = tid >> 1, sc = (tid & 1) * 16;
  const int wr = (wave >> 1) * 64, wc = (wave & 1) * 64;
  const int g = lane >> 4, li = lane & 15;

  const f32x4 fzero = {0.f, 0.f, 0.f, 0.f};
  f32x4 acc[4][4];
#pragma unroll
  for (int i = 0; i < 4; ++i)
#pragma unroll
    for (int j = 0; j < 4; ++j) acc[i][j] = fzero;

  const float* Ap = X + (size_t)(m0 + sr) * K + sc;
  const float* Bp = W + (size_t)(n0 + sr) * K + sc;
  float aR[16], bR[16];
  load16f(Ap, aR); load16f(Bp, bR);

#pragma unroll 1
  for (int kt = 0; kt < 8; ++kt) {
    store16_bf16(&As[sr * LD + sc], aR);
    store16_bf16(&Bs[sr * LD + sc], bR);
    __syncthreads();
    if (kt < 7) { Ap += 32; Bp += 32; load16f(Ap, aR); load16f(Bp, bR); }
    bf16x8 af[4], bfr[4];
#pragma unroll
    for (int t = 0; t < 4; ++t) {
      af[t]  = *(const bf16x8*)&As[(wr + t * 16 + li) * LD + g * 8];
      bfr[t] = *(const bf16x8*)&Bs[(wc + t * 16 + li) * LD + g * 8];
    }
#pragma unroll
    for (int i = 0; i < 4; ++i)
#pragma unroll
      for (int j = 0; j < 4; ++j)
        acc[i][j] = MFMA_BF16(af[i], bfr[j], acc[i][j]);
    __syncthreads();
  }

#pragma unroll
  for (int i = 0; i < 4; ++i) {
    const int row = m0 + wr + i * 16 + g * 4;
#pragma unroll
    for (int j = 0; j < 4; ++j) {
      const int col = n0 + wc + j * 16 + li;
      const float bv = bias[col];
      const int which = col >> 8;                 // 0=q 1=k 2=v
      if (which == 2) {
        const int hh = (col >> 5) & 7, c = col & 31;
        bf16x4 pv;
#pragma unroll
        for (int r = 0; r < 4; ++r) pv[r] = (bf16)(acc[i][j][r] + bv);
        *(bf16x4*)(Vb + (((size_t)(hh * 32 + c)) << 17) + row) = pv;
      } else {
        bf16* dst = which == 0 ? Qb : Kb;
        const size_t base = (size_t)((col >> 5) & 7) * (131072u * 32u) + (size_t)(col & 31);
#pragma unroll
        for (int r = 0; r < 4; ++r)
          dst[base + (size_t)(row + r) * 32u] = (bf16)(acc[i][j][r] + bv);
      }
    }
  }
}

// ---------------------------------------------------------------------------
// Kernel 2: window attention. Block = (window, head), 4 waves.
// Coalesced global -> LDS staging (K scattered to sigma-row order on the
// WRITE side; V^T staged once), then the verified round-2 math:
//   S^T tile = mfma(K_sigma, Q); in-register softmax (exp2 domain);
//   O^T = mfma(V^T, P^T) with P fully in-lane (sigma order). One barrier.
// ---------------------------------------------------------------------------
__global__ __launch_bounds__(256, 4)
void win_attn(const bf16* __restrict__ Qb, const bf16* __restrict__ Kb,
              const bf16* __restrict__ Vt, const float* __restrict__ biasF,
              bf16* __restrict__ Ob)
{
  constexpr int LDK = 40, LDV = 264;
  __shared__ bf16 Ks[256 * LDK];    // sigma-row order, 20480 B
  __shared__ bf16 Vs[32 * LDV];     // V^T [d][halo tok], 16896 B

  const int tid = threadIdx.x;
  const int lane = tid & 63, qt = tid >> 6;
  const int li = lane & 15, g = lane >> 4;
  const int bid = blockIdx.x;
  const int h = bid & 7, w = bid >> 3;      // head fastest: XCD x keeps head x
  const int b = w >> 8, wi = (w >> 4) & 15, wj = w & 15;
  const int btok = b << 14;

  // ---- stage K: coalesced global read, sigma-permuted LDS row write ----
  {
    const int hi = tid >> 4, hj = tid & 15;
    const int gi = wi * 8 - 4 + hi, gj = wj * 8 - 4 + hj;
    const bool ok = ((unsigned)gi < 128u) && ((unsigned)gj < 128u);
    const bf16* kg = Kb + ((((size_t)h) << 17) + (size_t)(btok + gi * 128 + gj)) * 32;
    const int i = ((hi & 1) << 3) | ((hj >> 3) << 2) | (hj & 3);
    const int kt = ((hi >> 1) << 1) | ((hj >> 2) & 1);
    bf16* dst = &Ks[(kt * 16 + i) * LDK];
    const uint4 z{};
#pragma unroll
    for (int c = 0; c < 4; ++c) {
      uint4 v = z;
      if (ok) v = *(const uint4*)(kg + c * 8);
      *(uint4*)(dst + c * 8) = v;
    }
  }
  // ---- stage V^T: 512 runs (d, hi) x 32B as predicated 8B segments ----
  {
    const bf16* vg = Vt + (((size_t)(h * 32)) << 17) + btok;
#pragma unroll
    for (int it = 0; it < 2; ++it) {
      const int ri = it * 256 + tid;
      const int dl = ri >> 4, hi = ri & 15;
      const int gi = wi * 8 - 4 + hi;
      const bool rok = (unsigned)gi < 128u;
      const int gj0 = wj * 8 - 4;
      bf16* ld = &Vs[dl * LDV + hi * 16];
#pragma unroll
      for (int cs = 0; cs < 4; ++cs) {
        const int gj = gj0 + cs * 4;
        bf16x4 v = {};
        if (rok && ((unsigned)gj < 128u))
          v = *(const bf16x4*)(vg + (((size_t)dl) << 17) + (size_t)(gi * 128 + gj));
        *(bf16x4*)(ld + cs * 4) = v;
      }
    }
  }

  // ---- Q fragment (B-operand), coalesced global ----
  const int q = qt * 16 + li;
  const int tokq = btok + (wi * 8 + (q >> 3)) * 128 + (wj * 8 + (q & 7));
  const bf16x8 qf = *(const bf16x8*)(Qb + ((((size_t)h) << 17) + tokq) * 32 + g * 8);

  __syncthreads();

  // ---- QK^T over 16 sigma-ordered key tiles (LDS reads, regular) ----
  const f32x4 z4 = {0.f, 0.f, 0.f, 0.f};
  f32x4 s[16];
#pragma unroll
  for (int kt = 0; kt < 16; ++kt) {
    const bf16x8 kf = *(const bf16x8*)&Ks[(kt * 16 + li) * LDK + g * 8];
    s[kt] = MFMA_BF16(kf, qf, z4);
  }

  // ---- scale*log2e + bias (bias pre-multiplied by log2e) ----
  const float scaleL = 0.17677669529663687f * 1.4426950408889634f;
  const float* bF = biasF + (size_t)(((h * 4 + qt) * 16 * 4 + g) * 16 + li) * 4;
#pragma unroll
  for (int kt = 0; kt < 16; ++kt) {
    const float4 bv = *(const float4*)(bF + kt * 256);
    s[kt][0] = s[kt][0] * scaleL + bv.x;
    s[kt][1] = s[kt][1] * scaleL + bv.y;
    s[kt][2] = s[kt][2] * scaleL + bv.z;
    s[kt][3] = s[kt][3] * scaleL + bv.w;
  }

  // ---- softmax over 256 keys: per-lane 64 + shfl_xor(16,32) ----
  float mx = -3.0e38f;
#pragma unroll
  for (int kt = 0; kt < 16; ++kt)
    mx = fmaxf(fmaxf(fmaxf(s[kt][0], s[kt][1]), fmaxf(s[kt][2], s[kt][3])), mx);
  mx = fmaxf(mx, __shfl_xor(mx, 16));
  mx = fmaxf(mx, __shfl_xor(mx, 32));

  float sum = 0.f;
  bf16x4 pk[16];
#pragma unroll
  for (int kt = 0; kt < 16; ++kt) {
    const float p0 = exp2f(s[kt][0] - mx);
    const float p1 = exp2f(s[kt][1] - mx);
    const float p2 = exp2f(s[kt][2] - mx);
    const float p3 = exp2f(s[kt][3] - mx);
    sum += (p0 + p1) + (p2 + p3);
    bf16x4 t; t[0] = (bf16)p0; t[1] = (bf16)p1; t[2] = (bf16)p2; t[3] = (bf16)p3;
    pk[kt] = t;
  }
  sum += __shfl_xor(sum, 16);
  sum += __shfl_xor(sum, 32);
  const float inv = __builtin_amdgcn_rcpf(sum);

  // ---- O^T = V^T * P^T (V^T from LDS, conflict-free b128) ----
  f32x4 o0 = z4, o1 = z4;
#pragma unroll
  for (int ks = 0; ks < 8; ++ks) {
    const int coff = (2 * ks + (g >> 1)) * 16 + 8 * (g & 1);
    const bf16x8 vf0 = *(const bf16x8*)&Vs[li * LDV + coff];
    const bf16x8 vf1 = *(const bf16x8*)&Vs[(li + 16) * LDV + coff];
    const bf16x8 pb = __builtin_shufflevector(pk[2 * ks], pk[2 * ks + 1],
                                              0, 1, 2, 3, 4, 5, 6, 7);
    o0 = MFMA_BF16(vf0, pb, o0);
    o1 = MFMA_BF16(vf1, pb, o1);
  }

  // ---- epilogue: O[tokq][h*32 + dt*16 + 4g + r] = O^T/sum ----
  bf16* op = Ob + (size_t)tokq * 256 + h * 32 + 4 * g;
  bf16x4 w0, w1;
#pragma unroll
  for (int r = 0; r < 4; ++r) {
    w0[r] = (bf16)(o0[r] * inv);
    w1[r] = (bf16)(o1[r] * inv);
  }
  *(bf16x4*)(op) = w0;
  *(bf16x4*)(op + 16) = w1;
}

// ---------------------------------------------------------------------------
// Kernel 3: out = attn_out @ proj_w.T + proj_b   (fp32 output to d_out)
// ---------------------------------------------------------------------------
__global__ __launch_bounds__(256, 2)
void proj_gemm(const bf16* __restrict__ A, const float* __restrict__ W,
               const float* __restrict__ bias, float* __restrict__ Out)
{
  constexpr int K = 256;
  constexpr int LD = 40;
  __shared__ bf16 As[128 * LD];
  __shared__ bf16 Bs[128 * LD];

  const int tid = threadIdx.x;
  const int lane = tid & 63, wave = tid >> 6;
  const int bn = blockIdx.x & 1, bm = blockIdx.x >> 1;
  const int m0 = bm * 128, n0 = bn * 128;
  const int sr = tid >> 1, sc = (tid & 1) * 16;
  const int wr = (wave >> 1) * 64, wc = (wave & 1) * 64;
  const int g = lane >> 4, li = lane & 15;

  const f32x4 fzero = {0.f, 0.f, 0.f, 0.f};
  f32x4 acc[4][4];
#pragma unroll
  for (int i = 0; i < 4; ++i)
#pragma unroll
    for (int j = 0; j < 4; ++j) acc[i][j] = fzero;

  const bf16* Ap = A + (size_t)(m0 + sr) * K + sc;
  const float* Bp = W + (size_t)(n0 + sr) * K + sc;
  uint4 aV0, aV1; float bR[16];
  aV0 = *(const uint4*)(Ap); aV1 = *(const uint4*)(Ap + 8);
  load16f(Bp, bR);

#pragma unroll 1
  for (int kt = 0; kt < 8; ++kt) {
    *(uint4*)&As[sr * LD + sc] = aV0;
    *(uint4*)&As[sr * LD + sc + 8] = aV1;
    store16_bf16(&Bs[sr * LD + sc], bR);
    __syncthreads();
    if (kt < 7) {
      Ap += 32; Bp += 32;
      aV0 = *(const uint4*)(Ap); aV1 = *(const uint4*)(Ap + 8);
      load16f(Bp, bR);
    }
    bf16x8 af[4], bfr[4];
#pragma unroll
    for (int t = 0; t < 4; ++t) {
      af[t]  = *(const bf16x8*)&As[(wr + t * 16 + li) * LD + g * 8];
      bfr[t] = *(const bf16x8*)&Bs[(wc + t * 16 + li) * LD + g * 8];
    }
#pragma unroll
    for (int i = 0; i < 4; ++i)
#pragma unroll
      for (int j = 0; j < 4; ++j)
        acc[i][j] = MFMA_BF16(af[i], bfr[j], acc[i][j]);
    __syncthreads();
  }

#pragma unroll
  for (int i = 0; i < 4; ++i) {
    const int row = m0 + wr + i * 16 + g * 4;
#pragma unroll
    for (int j = 0; j < 4; ++j) {
      const int col = n0 + wc + j * 16 + li;
      const float bv = bias[col];
#pragma unroll
      for (int r = 0; r < 4; ++r)
        Out[(size_t)(row + r) * 256 + col] = acc[i][j][r] + bv;
    }
  }
}

// ---------------------------------------------------------------------------
extern "C" void kernel_launch(void* const* d_in, const int* in_sizes, int n_in,
                              void* d_out, int out_size, void* d_ws, size_t ws_size,
                              hipStream_t stream)
{
  const float* x       = (const float*)d_in[0];
  // d_in[1] = mask: unused by the reference
  const float* qkv_w   = (const float*)d_in[2];
  const float* qkv_b   = (const float*)d_in[3];
  const float* proj_w  = (const float*)d_in[4];
  const float* proj_b  = (const float*)d_in[5];
  const float* rel_tab = (const float*)d_in[6];
  float* out = (float*)d_out;

  char* ws = (char*)d_ws;
  bf16* Qb = (bf16*)(ws);                            // [8h][131072][32]   64 MiB
  bf16* Kb = (bf16*)(ws + (size_t)67108864);         // [8h][131072][32]   64 MiB
  bf16* Vt = (bf16*)(ws + (size_t)134217728);        // [8h*32d][131072]   64 MiB
  bf16* Ao = (bf16*)(ws + (size_t)201326592);        // [131072][256]      64 MiB
  float* biasF = (float*)d_out;  // 512 KB scratch, overwritten by proj_gemm

  bias_pre<<<dim3(128), dim3(256), 0, stream>>>(rel_tab, biasF);
  qkv_gemm<<<dim3(6144), dim3(256), 0, stream>>>(x, qkv_w, qkv_b, Qb, Kb, Vt);
  win_attn<<<dim3(16384), dim3(256), 0, stream>>>(Qb, Kb, Vt, biasF, Ao);
  proj_gemm<<<dim3(2048), dim3(256), 0, stream>>>(Ao, proj_w, proj_b, out);
}